// Round 13
// baseline (255.278 us; speedup 1.0000x reference)
//
#include <hip/hip_runtime.h>
#include <hip/hip_fp16.h>

#define FEAT 32
#define BIN_NODES 128
#define BIN_SHIFT 7
#define TILE_EDGES 8192   // edges per build block
#define BWAVES 16         // waves per build block (1024 threads)
#define KEYS 256          // dst_local (7b) x src-half (1b)
#define SRC_BITS 20
#define SRC_MASK 0xFFFFF

// Block-local int64-vs-int32 detection: odd 32-bit words of an int64 index
// array (values < 2^31) are all zero; for int32 they are random node ids.
__device__ __forceinline__ int block_detect_int64(const int* __restrict__ raw32, int* nz) {
    if (threadIdx.x == 0) *nz = 0;
    __syncthreads();
    if (raw32[2 * threadIdx.x + 1] != 0) *nz = 1;
    __syncthreads();
    return (*nz == 0) ? 1 : 0;
}

__device__ __forceinline__ int load_idx(const void* raw, int f, long long i) {
    return f ? (int)((const long long*)raw)[i] : ((const int*)raw)[i];
}

// Phase A: per-(tile,bin) histogram, 16 wave-private copies (1024 threads).
__global__ __launch_bounds__(1024)
void binA_kernel(const void* __restrict__ raw, int* __restrict__ mat, int e, int nb) {
    extern __shared__ int hist[];  // BWAVES*nb + 1
    int t = threadIdx.x;
    for (int i = t; i < BWAVES * nb; i += 1024) hist[i] = 0;
    int f = block_detect_int64((const int*)raw, &hist[BWAVES * nb]);
    int w = t >> 6, lane = t & 63;
    long long base = (long long)blockIdx.x * TILE_EDGES;
    int cnt = (int)min((long long)TILE_EDGES, (long long)e - base);
    int* hw = hist + w * nb;
    const int seg = TILE_EDGES / BWAVES;  // 512 edges per wave
    int wbeg = w * seg;
    int wend = min(wbeg + seg, cnt);
    for (int i = wbeg + lane; i < wend; i += 64) {
        int d = load_idx(raw, f, (long long)e + base + i);
        atomicAdd(&hw[d >> BIN_SHIFT], 1);
    }
    __syncthreads();
    for (int b = t; b < nb; b += 1024) {
        int s = 0;
#pragma unroll
        for (int w2 = 0; w2 < BWAVES; ++w2) s += hist[w2 * nb + b];
        mat[blockIdx.x * nb + b] = s;
    }
}

// logical L = b*nblk + k (bin-major) <-> physical p = k*nb + b
__device__ __forceinline__ int l2p(int L, int nb, int nblk) {
    int b = L / nblk;
    int k = L - b * nblk;
    return k * nb + b;
}

__global__ void scan1_kernel(int* __restrict__ mat, int* __restrict__ bsum,
                             int M, int nb, int nblk) {
    __shared__ int sd[256];
    int t = threadIdx.x;
    int L = blockIdx.x * 256 + t;
    int p = 0, v = 0;
    if (L < M) { p = l2p(L, nb, nblk); v = mat[p]; }
    sd[t] = v;
    __syncthreads();
    for (int off = 1; off < 256; off <<= 1) {
        int add = (t >= off) ? sd[t - off] : 0;
        __syncthreads();
        sd[t] += add;
        __syncthreads();
    }
    if (L < M) mat[p] = sd[t] - v;   // exclusive within scan-block
    if (t == 255) bsum[blockIdx.x] = sd[t];
}

__global__ void scan2_kernel(int* __restrict__ bsum, int nbks) {
    __shared__ int sd[1024];
    int t = threadIdx.x;
    int v = (t < nbks) ? bsum[t] : 0;
    sd[t] = v;
    __syncthreads();
    for (int off = 1; off < 1024; off <<= 1) {
        int add = (t >= off) ? sd[t - off] : 0;
        __syncthreads();
        sd[t] += add;
        __syncthreads();
    }
    if (t < nbks) bsum[t] = sd[t] - v;
}

// Phase C: scatter packed records grouped by bin (1024 threads; block-shared
// cursors). rec = src | dst_local<<20.
__global__ __launch_bounds__(1024)
void binC_kernel(const void* __restrict__ raw, const int* __restrict__ mat,
                 const int* __restrict__ bsum, int* __restrict__ packed,
                 int e, int nb, int nblk) {
    extern __shared__ int cur[];  // nb + 1
    int t = threadIdx.x;
    int f = block_detect_int64((const int*)raw, &cur[nb]);
    for (int i = t; i < nb; i += 1024)
        cur[i] = mat[blockIdx.x * nb + i] + bsum[(i * nblk + blockIdx.x) >> 8];
    __syncthreads();
    long long base = (long long)blockIdx.x * TILE_EDGES;
    int cnt = (int)min((long long)TILE_EDGES, (long long)e - base);
    for (int i = t; i < cnt; i += 1024) {
        long long ei = base + i;
        int s = load_idx(raw, f, ei);
        int d = load_idx(raw, f, (long long)e + ei);
        int b = d >> BIN_SHIFT;
        int pos = atomicAdd(&cur[b], 1);
        packed[pos] = s | ((d & (BIN_NODES - 1)) << SRC_BITS);
    }
}

// Per-bin 256-key counting sort (key = dst_local*2 | src_half) -> per-node CSR
// with A-segment (src < nhalf) then B-segment, plus fused layer-1 matmul.
__global__ __launch_bounds__(1024)
void degsort_kernel(const int* __restrict__ packed, const int* __restrict__ mat,
                    const int* __restrict__ bsum, const float* __restrict__ x,
                    const float* __restrict__ W1, float* __restrict__ dis,
                    int* __restrict__ row_start, int* __restrict__ row_mid,
                    int* __restrict__ recs, __half* __restrict__ h1,
                    int e, int n, int nhalf, int nb, int nblk) {
    __shared__ int cnt[BWAVES][KEYS];   // 16 KB
    __shared__ int wcur[BWAVES][KEYS];  // 16 KB
    __shared__ int exc[KEYS];           // 1 KB
    __shared__ float Wl[FEAT * FEAT];      // 4 KB
    __shared__ float xs[BIN_NODES * FEAT]; // 16 KB
    __shared__ float disS[BIN_NODES];
    int b = blockIdx.x, t = threadIdx.x;
    int w = t >> 6;
    int nodebase = b * BIN_NODES;
    for (int i = t; i < BWAVES * KEYS; i += 1024) ((int*)cnt)[i] = 0;
    for (int i = t; i < FEAT * FEAT; i += 1024) Wl[i] = W1[i];
    {
        int lim = min(BIN_NODES * FEAT, (n - nodebase) * FEAT);
        for (int i = t; i < lim; i += 1024) xs[i] = x[(size_t)nodebase * FEAT + i];
    }
    __syncthreads();
    int start = mat[b] + bsum[(b * nblk) >> 8];
    int end = (b + 1 < nb) ? (mat[b + 1] + bsum[((b + 1) * nblk) >> 8]) : e;
    for (int i = start + t; i < end; i += 1024) {
        int rec = packed[i];
        int key = ((rec >> SRC_BITS) << 1) | ((rec & SRC_MASK) >= nhalf ? 1 : 0);
        atomicAdd(&cnt[w][key], 1);
    }
    __syncthreads();
    if (t < KEYS) {
        int s = 0;
#pragma unroll
        for (int w2 = 0; w2 < BWAVES; ++w2) s += cnt[w2][t];
        exc[t] = s;
    }
    __syncthreads();
    for (int off = 1; off < KEYS; off <<= 1) {
        int v = 0;
        if (t < KEYS && t >= off) v = exc[t - off];
        __syncthreads();
        if (t < KEYS) exc[t] += v;   // inclusive scan
        __syncthreads();
    }
    if (t < KEYS) {
        int tot = 0;
#pragma unroll
        for (int w2 = 0; w2 < BWAVES; ++w2) tot += cnt[w2][t];
        int base_k = start + exc[t] - tot;
        int run = base_k;
#pragma unroll
        for (int w2 = 0; w2 < BWAVES; ++w2) { wcur[w2][t] = run; run += cnt[w2][t]; }
    }
    __syncthreads();
    if (t < BIN_NODES) {
        int totA = 0, totB = 0;
#pragma unroll
        for (int w2 = 0; w2 < BWAVES; ++w2) { totA += cnt[w2][2 * t]; totB += cnt[w2][2 * t + 1]; }
        int rs = start + exc[2 * t] - totA;
        float dval = rsqrtf((float)(totA + totB) + 1.0f);
        disS[t] = dval;
        int node = nodebase + t;
        if (node < n) {
            dis[node] = dval;
            row_start[node] = rs;
            row_mid[node] = start + exc[2 * t];  // end of A-segment
        }
    }
    if (b == 0 && t == 512) row_start[n] = e;  // sentinel
    __syncthreads();
    for (int i = start + t; i < end; i += 1024) {
        int rec = packed[i];
        int src = rec & SRC_MASK;
        int key = ((rec >> SRC_BITS) << 1) | (src >= nhalf ? 1 : 0);
        int pos = atomicAdd(&wcur[w][key], 1);
        recs[pos] = src;
    }
    // fused layer-1 matmul (xs/Wl/disS synced above; sort pass touches only wcur/global)
    for (int idx = t; idx < BIN_NODES * FEAT; idx += 1024) {
        int nl = idx >> 5, j = idx & 31;
        int node = nodebase + nl;
        if (node >= n) break;
        float sum = 0.0f;
#pragma unroll
        for (int k = 0; k < FEAT; ++k) sum = fmaf(xs[nl * FEAT + k], Wl[k * FEAT + j], sum);
        h1[(size_t)node * FEAT + j] = __float2half(disS[nl] * sum);
    }
}

// Layer-2 matmul: h2 = fp16( dis * (relu(acc1h) @ W2) ), acc1h is fp16.
__global__ void matmul2_kernel(const __half* __restrict__ in, const float* __restrict__ W,
                               const float* __restrict__ dis, __half* __restrict__ h,
                               int n) {
    __shared__ float Wl[FEAT * FEAT];
    int tid = threadIdx.x;
    for (int i = tid; i < FEAT * FEAT; i += 256) Wl[i] = W[i];
    __syncthreads();
    int node = blockIdx.x * 8 + (tid >> 5);
    int j = tid & 31;
    if (node >= n) return;
    float xv = fmaxf(__half2float(in[(size_t)node * FEAT + j]), 0.0f);
    float sum = 0.0f;
#pragma unroll
    for (int k = 0; k < FEAT; ++k) sum = fmaf(__shfl(xv, k, 32), Wl[k * FEAT + j], sum);
    h[(size_t)node * FEAT + j] = __float2half(dis[node] * sum);
}

// Two-phase pull. PHASE 0: gather A-segment (src < nhalf -> 3.2MB working set,
// per-XCD-L2-resident), + self-loop if node<nhalf, write raw fp32 partial.
// PHASE 1: gather B-segment, + self if node>=nhalf, + partial, scale/bias/act.
// 32 lanes/node = 8 record-slots x 4 feature-lanes; window 32 records =
// 1 int4 rec load + 4 predicated 16B gathers per lane.
template <int PHASE, int OUT_FP16>
__global__ __launch_bounds__(256, 6)
void pull_kernel(const int* __restrict__ recs, const int* __restrict__ row_start,
                 const int* __restrict__ row_mid, const __half* __restrict__ h,
                 const float* __restrict__ dis, const float* __restrict__ bias,
                 float* __restrict__ partial, void* __restrict__ outp,
                 int n, int nhalf) {
    int t = threadIdx.x;
    int node = blockIdx.x * 8 + (t >> 5);
    if (node >= n) return;
    int l32 = t & 31;
    int sub = l32 >> 2;   // record slot 0..7, owns 4 contiguous records
    int fb = l32 & 3;     // float4 feature block (8 halves)
    int segS, segE;
    if (PHASE == 0) { segS = row_start[node]; segE = row_mid[node]; }
    else            { segS = row_mid[node];   segE = row_start[node + 1]; }
    int deg = segE - segS;
    const float4* h4 = (const float4*)h;
    float s0 = 0, s1 = 0, s2 = 0, s3 = 0, s4 = 0, s5 = 0, s6 = 0, s7 = 0;
    for (int r0 = 0; r0 < deg; r0 += 32) {
        int rbase = r0 + sub * 4;
        int4 ra = *(const int4*)&recs[segS + rbase];  // padded recs: safe over-read
        int ridx[4] = {ra.x, ra.y, ra.z, ra.w};
#pragma unroll
        for (int w = 0; w < 4; ++w) {
            if (rbase + w < deg) {
                float4 v = h4[(size_t)ridx[w] * 4 + fb];
                const __half2* hp = (const __half2*)&v;
                float2 a = __half22float2(hp[0]);
                float2 b = __half22float2(hp[1]);
                float2 c = __half22float2(hp[2]);
                float2 d = __half22float2(hp[3]);
                s0 += a.x; s1 += a.y; s2 += b.x; s3 += b.y;
                s4 += c.x; s5 += c.y; s6 += d.x; s7 += d.y;
            }
        }
    }
#pragma unroll
    for (int m = 4; m <= 16; m <<= 1) {
        s0 += __shfl_xor(s0, m, 64); s1 += __shfl_xor(s1, m, 64);
        s2 += __shfl_xor(s2, m, 64); s3 += __shfl_xor(s3, m, 64);
        s4 += __shfl_xor(s4, m, 64); s5 += __shfl_xor(s5, m, 64);
        s6 += __shfl_xor(s6, m, 64); s7 += __shfl_xor(s7, m, 64);
    }
    if (sub == 0) {
        // self-loop handled in the phase owning this node's half (locality)
        bool selfhere = (PHASE == 0) ? (node < nhalf) : (node >= nhalf);
        if (selfhere) {
            float4 hv = h4[(size_t)node * 4 + fb];
            const __half2* hp = (const __half2*)&hv;
            float2 a = __half22float2(hp[0]);
            float2 b = __half22float2(hp[1]);
            float2 c = __half22float2(hp[2]);
            float2 d = __half22float2(hp[3]);
            s0 += a.x; s1 += a.y; s2 += b.x; s3 += b.y;
            s4 += c.x; s5 += c.y; s6 += d.x; s7 += d.y;
        }
        if (PHASE == 0) {
            float4 p0 = make_float4(s0, s1, s2, s3);
            float4 p1 = make_float4(s4, s5, s6, s7);
            ((float4*)partial)[(size_t)node * 8 + fb * 2] = p0;
            ((float4*)partial)[(size_t)node * 8 + fb * 2 + 1] = p1;
        } else {
            float4 p0 = ((const float4*)partial)[(size_t)node * 8 + fb * 2];
            float4 p1 = ((const float4*)partial)[(size_t)node * 8 + fb * 2 + 1];
            float dn = dis[node];
            const float4* bv4 = (const float4*)bias;
            float4 b0 = bv4[fb * 2], b1 = bv4[fb * 2 + 1];
            float v0 = fmaf(dn, s0 + p0.x, b0.x);
            float v1 = fmaf(dn, s1 + p0.y, b0.y);
            float v2 = fmaf(dn, s2 + p0.z, b0.z);
            float v3 = fmaf(dn, s3 + p0.w, b0.w);
            float v4 = fmaf(dn, s4 + p1.x, b1.x);
            float v5 = fmaf(dn, s5 + p1.y, b1.y);
            float v6 = fmaf(dn, s6 + p1.z, b1.z);
            float v7 = fmaf(dn, s7 + p1.w, b1.w);
            if (OUT_FP16) {
                // layer-1 intermediate: pre-relu (matmul2 applies relu on read)
                union { __half2 hh[4]; float4 f; } u;
                u.hh[0] = __floats2half2_rn(v0, v1);
                u.hh[1] = __floats2half2_rn(v2, v3);
                u.hh[2] = __floats2half2_rn(v4, v5);
                u.hh[3] = __floats2half2_rn(v6, v7);
                ((float4*)outp)[(size_t)node * 4 + fb] = u.f;
            } else {
                float4 o0, o1;
                o0.x = fmaxf(v0, 0.0f); o0.y = fmaxf(v1, 0.0f);
                o0.z = fmaxf(v2, 0.0f); o0.w = fmaxf(v3, 0.0f);
                o1.x = fmaxf(v4, 0.0f); o1.y = fmaxf(v5, 0.0f);
                o1.z = fmaxf(v6, 0.0f); o1.w = fmaxf(v7, 0.0f);
                ((float4*)outp)[(size_t)node * 8 + fb * 2] = o0;
                ((float4*)outp)[(size_t)node * 8 + fb * 2 + 1] = o1;
            }
        }
    }
}

extern "C" void kernel_launch(void* const* d_in, const int* in_sizes, int n_in,
                              void* d_out, int out_size, void* d_ws, size_t ws_size,
                              hipStream_t stream) {
    const float* x = (const float*)d_in[0];
    const void* eidx_raw = d_in[1];
    const float* W1 = (const float*)d_in[2];
    const float* b1 = (const float*)d_in[3];
    const float* W2 = (const float*)d_in[4];
    const float* b2 = (const float*)d_in[5];
    float* out = (float*)d_out;

    const int n = in_sizes[0] / FEAT;                    // 100000
    const int e = in_sizes[1] / 2;                       // 1600000
    const int nhalf = n / 2;
    const int nb = (n + BIN_NODES - 1) / BIN_NODES;      // 782
    const int nblk = (e + TILE_EDGES - 1) / TILE_EDGES;  // 196
    const int M = nb * nblk;                             // 153k
    const int nbks = (M + 255) / 256;                    // 599 <= 1024

    // Workspace (256B-aligned). `packed` aliases `acc1h` region (packed dead
    // after degsort; acc1h first written by pullB1). partial is separate.
    char* ws = (char*)d_ws;
    size_t off = 0;
    auto alloc = [&](size_t bytes) { char* p = ws + off; off = (off + bytes + 255) & ~(size_t)255; return p; };
    int*    mat       = (int*)   alloc((size_t)M * 4);
    int*    bsum      = (int*)   alloc((size_t)nbks * 4);
    float*  dis       = (float*) alloc((size_t)n * 4);
    int*    row_start = (int*)   alloc((size_t)(n + 1) * 4);
    int*    row_mid   = (int*)   alloc((size_t)n * 4);
    int*    recs      = (int*)   alloc((size_t)(e + 64) * 4);  // +64 pad for int4 over-read
    __half* h         = (__half*)alloc((size_t)n * FEAT * 2);
    float*  partial   = (float*) alloc((size_t)n * FEAT * 4);
    char*   big       =          alloc((size_t)e * 4);          // packed / acc1h share
    int*    packed    = (int*)big;
    __half* acc1h     = (__half*)big;   // n*32*2 = 6.4MB == e*4

    const size_t ldsA = (size_t)(BWAVES * nb + 1) * 4;   // ~50 KB
    const size_t ldsC = (size_t)(nb + 1) * 4;            // ~3.1 KB
    const int gNode = (n + 7) / 8;

    // CSR build + fused layer-1 matmul (5 launches)
    binA_kernel<<<nblk, 1024, ldsA, stream>>>(eidx_raw, mat, e, nb);
    scan1_kernel<<<nbks, 256, 0, stream>>>(mat, bsum, M, nb, nblk);
    scan2_kernel<<<1, 1024, 0, stream>>>(bsum, nbks);
    binC_kernel<<<nblk, 1024, ldsC, stream>>>(eidx_raw, mat, bsum, packed, e, nb, nblk);
    degsort_kernel<<<nb, 1024, 0, stream>>>(packed, mat, bsum, x, W1, dis, row_start,
                                            row_mid, recs, h, e, n, nhalf, nb, nblk);

    // Layer 1: phased pulls (A = lower-half sources, B = upper) -> fp16 acc1h
    pull_kernel<0, 0><<<gNode, 256, 0, stream>>>(recs, row_start, row_mid, h, dis, b1,
                                                 partial, acc1h, n, nhalf);
    pull_kernel<1, 1><<<gNode, 256, 0, stream>>>(recs, row_start, row_mid, h, dis, b1,
                                                 partial, acc1h, n, nhalf);
    // Layer 2
    matmul2_kernel<<<gNode, 256, 0, stream>>>(acc1h, W2, dis, h, n);
    pull_kernel<0, 0><<<gNode, 256, 0, stream>>>(recs, row_start, row_mid, h, dis, b2,
                                                 partial, out, n, nhalf);
    pull_kernel<1, 0><<<gNode, 256, 0, stream>>>(recs, row_start, row_mid, h, dis, b2,
                                                 partial, out, n, nhalf);
}

// Round 14
// 232.398 us; speedup vs baseline: 1.0984x; 1.0984x over previous
//
#include <hip/hip_runtime.h>
#include <hip/hip_fp16.h>

#define FEAT 32
#define BIN_NODES 128
#define BIN_SHIFT 7
#define TILE_EDGES 8192   // edges per build block
#define BWAVES 16         // waves per build block (1024 threads)
#define SRC_BITS 20
#define SRC_MASK 0xFFFFF

// Block-local int64-vs-int32 detection: odd 32-bit words of an int64 index
// array (values < 2^31) are all zero; for int32 they are random node ids.
__device__ __forceinline__ int block_detect_int64(const int* __restrict__ raw32, int* nz) {
    if (threadIdx.x == 0) *nz = 0;
    __syncthreads();
    if (raw32[2 * threadIdx.x + 1] != 0) *nz = 1;
    __syncthreads();
    return (*nz == 0) ? 1 : 0;
}

__device__ __forceinline__ int load_idx(const void* raw, int f, long long i) {
    return f ? (int)((const long long*)raw)[i] : ((const int*)raw)[i];
}

// Phase A: per-(tile,bin) histogram, 16 wave-private copies (1024 threads).
__global__ __launch_bounds__(1024)
void binA_kernel(const void* __restrict__ raw, int* __restrict__ mat, int e, int nb) {
    extern __shared__ int hist[];  // BWAVES*nb + 1
    int t = threadIdx.x;
    for (int i = t; i < BWAVES * nb; i += 1024) hist[i] = 0;
    int f = block_detect_int64((const int*)raw, &hist[BWAVES * nb]);
    int w = t >> 6, lane = t & 63;
    long long base = (long long)blockIdx.x * TILE_EDGES;
    int cnt = (int)min((long long)TILE_EDGES, (long long)e - base);
    int* hw = hist + w * nb;
    const int seg = TILE_EDGES / BWAVES;  // 512 edges per wave
    int wbeg = w * seg;
    int wend = min(wbeg + seg, cnt);
    for (int i = wbeg + lane; i < wend; i += 64) {
        int d = load_idx(raw, f, (long long)e + base + i);
        atomicAdd(&hw[d >> BIN_SHIFT], 1);
    }
    __syncthreads();
    for (int b = t; b < nb; b += 1024) {
        int s = 0;
#pragma unroll
        for (int w2 = 0; w2 < BWAVES; ++w2) s += hist[w2 * nb + b];
        mat[blockIdx.x * nb + b] = s;
    }
}

// logical L = b*nblk + k (bin-major) <-> physical p = k*nb + b
__device__ __forceinline__ int l2p(int L, int nb, int nblk) {
    int b = L / nblk;
    int k = L - b * nblk;
    return k * nb + b;
}

__global__ void scan1_kernel(int* __restrict__ mat, int* __restrict__ bsum,
                             int M, int nb, int nblk) {
    __shared__ int sd[256];
    int t = threadIdx.x;
    int L = blockIdx.x * 256 + t;
    int p = 0, v = 0;
    if (L < M) { p = l2p(L, nb, nblk); v = mat[p]; }
    sd[t] = v;
    __syncthreads();
    for (int off = 1; off < 256; off <<= 1) {
        int add = (t >= off) ? sd[t - off] : 0;
        __syncthreads();
        sd[t] += add;
        __syncthreads();
    }
    if (L < M) mat[p] = sd[t] - v;   // exclusive within scan-block
    if (t == 255) bsum[blockIdx.x] = sd[t];
}

__global__ void scan2_kernel(int* __restrict__ bsum, int nbks) {
    __shared__ int sd[1024];
    int t = threadIdx.x;
    int v = (t < nbks) ? bsum[t] : 0;
    sd[t] = v;
    __syncthreads();
    for (int off = 1; off < 1024; off <<= 1) {
        int add = (t >= off) ? sd[t - off] : 0;
        __syncthreads();
        sd[t] += add;
        __syncthreads();
    }
    if (t < nbks) bsum[t] = sd[t] - v;
}

// Phase C: scatter packed records grouped by bin (1024 threads; block-shared
// cursors). rec = src | dst_local<<20.
__global__ __launch_bounds__(1024)
void binC_kernel(const void* __restrict__ raw, const int* __restrict__ mat,
                 const int* __restrict__ bsum, int* __restrict__ packed,
                 int e, int nb, int nblk) {
    extern __shared__ int cur[];  // nb + 1
    int t = threadIdx.x;
    int f = block_detect_int64((const int*)raw, &cur[nb]);
    for (int i = t; i < nb; i += 1024)
        cur[i] = mat[blockIdx.x * nb + i] + bsum[(i * nblk + blockIdx.x) >> 8];
    __syncthreads();
    long long base = (long long)blockIdx.x * TILE_EDGES;
    int cnt = (int)min((long long)TILE_EDGES, (long long)e - base);
    for (int i = t; i < cnt; i += 1024) {
        long long ei = base + i;
        int s = load_idx(raw, f, ei);
        int d = load_idx(raw, f, (long long)e + ei);
        int b = d >> BIN_SHIFT;
        int pos = atomicAdd(&cur[b], 1);
        packed[pos] = s | ((d & (BIN_NODES - 1)) << SRC_BITS);
    }
}

// Per-bin: 16 wave-private LDS histograms -> scan -> dis/row_start + per-wave
// base cursors, then contention-free counting-sort (recs = src, 4B).
__global__ __launch_bounds__(1024)
void degsort_kernel(const int* __restrict__ packed, const int* __restrict__ mat,
                    const int* __restrict__ bsum, float* __restrict__ dis,
                    int* __restrict__ row_start, int* __restrict__ recs,
                    int e, int n, int nb, int nblk) {
    __shared__ int cnt[BWAVES][BIN_NODES];
    __shared__ int wcur[BWAVES][BIN_NODES];
    __shared__ int exc[BIN_NODES];
    int b = blockIdx.x, t = threadIdx.x;
    int w = t >> 6;
    for (int i = t; i < BWAVES * BIN_NODES; i += 1024) ((int*)cnt)[i] = 0;
    __syncthreads();
    int start = mat[b] + bsum[(b * nblk) >> 8];
    int end = (b + 1 < nb) ? (mat[b + 1] + bsum[((b + 1) * nblk) >> 8]) : e;
    for (int i = start + t; i < end; i += 1024)
        atomicAdd(&cnt[w][packed[i] >> SRC_BITS], 1);
    __syncthreads();
    if (t < BIN_NODES) {
        int s = 0;
#pragma unroll
        for (int w2 = 0; w2 < BWAVES; ++w2) s += cnt[w2][t];
        exc[t] = s;
    }
    __syncthreads();
    for (int off = 1; off < BIN_NODES; off <<= 1) {
        int v = 0;
        if (t < BIN_NODES && t >= off) v = exc[t - off];
        __syncthreads();
        if (t < BIN_NODES) exc[t] += v;
        __syncthreads();
    }
    if (t < BIN_NODES) {
        int tot = 0;
#pragma unroll
        for (int w2 = 0; w2 < BWAVES; ++w2) tot += cnt[w2][t];
        int rs = start + exc[t] - tot;   // inclusive -> exclusive
        int run = rs;
#pragma unroll
        for (int w2 = 0; w2 < BWAVES; ++w2) { wcur[w2][t] = run; run += cnt[w2][t]; }
        int node = b * BIN_NODES + t;
        if (node < n) {
            dis[node] = rsqrtf((float)tot + 1.0f);
            row_start[node] = rs;
        }
    }
    if (b == 0 && t == 128) row_start[n] = e;  // sentinel
    __syncthreads();
    for (int i = start + t; i < end; i += 1024) {
        int rec = packed[i];
        int pos = atomicAdd(&wcur[w][rec >> SRC_BITS], 1);
        recs[pos] = rec & SRC_MASK;
    }
}

// h~ = fp16( dis * (act(in) @ W) )   (8 nodes x 32 lanes per block, W in LDS)
__global__ void matmul_kernel(const float* __restrict__ in, const float* __restrict__ W,
                              const float* __restrict__ dis, __half* __restrict__ h,
                              int n, int relu_in) {
    __shared__ float Wl[FEAT * FEAT];
    int tid = threadIdx.x;
    for (int i = tid; i < FEAT * FEAT; i += 256) Wl[i] = W[i];
    __syncthreads();
    int node = blockIdx.x * 8 + (tid >> 5);
    int j = tid & 31;
    if (node >= n) return;
    float xv = in[node * FEAT + j];
    if (relu_in) xv = fmaxf(xv, 0.0f);
    float sum = 0.0f;
#pragma unroll
    for (int k = 0; k < FEAT; ++k) sum = fmaf(__shfl(xv, k, 32), Wl[k * FEAT + j], sum);
    h[node * FEAT + j] = __float2half(dis[node] * sum);
}

// Pull: out[d] = act( dis[d] * (sum_{s in N(d)} h~[s] + h~[d]) + bias ).
// 32 lanes/node = 8 record-slots x 4 feature-lanes (float4 = 8 halves each);
// slots interleave over the window (slot sub owns records sub, sub+8, ...) so
// average-degree rows keep ALL 8 slots issuing gathers (max MLP). 8 predicated
// 16B gathers in flight per lane. launch_bounds(256,8): lean kernel fits <=64
// VGPRs -> 32 waves/CU to hide L2-miss latency (pulls are latency-bound).
__global__ __launch_bounds__(256, 8)
void pull_kernel(const int* __restrict__ recs, const int* __restrict__ row_start,
                 const __half* __restrict__ h, const float* __restrict__ dis,
                 const float* __restrict__ bias, float* __restrict__ out,
                 int n, int relu_out) {
    int t = threadIdx.x;
    int node = blockIdx.x * 8 + (t >> 5);
    if (node >= n) return;
    int l32 = t & 31;
    int sub = l32 >> 2;   // record slot 0..7
    int fb = l32 & 3;     // float4 feature block (8 halves)
    int start = row_start[node];
    int deg = row_start[node + 1] - start;
    const float4* h4 = (const float4*)h;  // 8 halves per float4, 4 per row
    float s0 = 0, s1 = 0, s2 = 0, s3 = 0, s4 = 0, s5 = 0, s6 = 0, s7 = 0;
    for (int r0 = 0; r0 < deg; r0 += 64) {
#pragma unroll
        for (int w = 0; w < 8; ++w) {
            int r = r0 + w * 8 + sub;
            if (r < deg) {
                int s = recs[start + r];
                float4 v = h4[(size_t)s * 4 + fb];
                const __half2* hp = (const __half2*)&v;
                float2 a = __half22float2(hp[0]);
                float2 b = __half22float2(hp[1]);
                float2 c = __half22float2(hp[2]);
                float2 d = __half22float2(hp[3]);
                s0 += a.x; s1 += a.y; s2 += b.x; s3 += b.y;
                s4 += c.x; s5 += c.y; s6 += d.x; s7 += d.y;
            }
        }
    }
    // reduce across the 8 record slots (xor 4,8,16 stays within the 32-group)
#pragma unroll
    for (int m = 4; m <= 16; m <<= 1) {
        s0 += __shfl_xor(s0, m, 64); s1 += __shfl_xor(s1, m, 64);
        s2 += __shfl_xor(s2, m, 64); s3 += __shfl_xor(s3, m, 64);
        s4 += __shfl_xor(s4, m, 64); s5 += __shfl_xor(s5, m, 64);
        s6 += __shfl_xor(s6, m, 64); s7 += __shfl_xor(s7, m, 64);
    }
    if (sub == 0) {
        float dn = dis[node];
        float4 hv = h4[(size_t)node * 4 + fb];   // self-loop: + h~[node]
        const __half2* hp = (const __half2*)&hv;
        float2 a = __half22float2(hp[0]);
        float2 b = __half22float2(hp[1]);
        float2 c = __half22float2(hp[2]);
        float2 d = __half22float2(hp[3]);
        const float4* bv4 = (const float4*)bias;
        float4 b0 = bv4[fb * 2], b1 = bv4[fb * 2 + 1];
        float4 o0, o1;
        o0.x = fmaf(dn, s0 + a.x, b0.x);
        o0.y = fmaf(dn, s1 + a.y, b0.y);
        o0.z = fmaf(dn, s2 + b.x, b0.z);
        o0.w = fmaf(dn, s3 + b.y, b0.w);
        o1.x = fmaf(dn, s4 + c.x, b1.x);
        o1.y = fmaf(dn, s5 + c.y, b1.y);
        o1.z = fmaf(dn, s6 + d.x, b1.z);
        o1.w = fmaf(dn, s7 + d.y, b1.w);
        if (relu_out) {
            o0.x = fmaxf(o0.x, 0.0f); o0.y = fmaxf(o0.y, 0.0f);
            o0.z = fmaxf(o0.z, 0.0f); o0.w = fmaxf(o0.w, 0.0f);
            o1.x = fmaxf(o1.x, 0.0f); o1.y = fmaxf(o1.y, 0.0f);
            o1.z = fmaxf(o1.z, 0.0f); o1.w = fmaxf(o1.w, 0.0f);
        }
        ((float4*)out)[(size_t)node * 8 + fb * 2] = o0;
        ((float4*)out)[(size_t)node * 8 + fb * 2 + 1] = o1;
    }
}

extern "C" void kernel_launch(void* const* d_in, const int* in_sizes, int n_in,
                              void* d_out, int out_size, void* d_ws, size_t ws_size,
                              hipStream_t stream) {
    const float* x = (const float*)d_in[0];
    const void* eidx_raw = d_in[1];
    const float* W1 = (const float*)d_in[2];
    const float* b1 = (const float*)d_in[3];
    const float* W2 = (const float*)d_in[4];
    const float* b2 = (const float*)d_in[5];
    float* out = (float*)d_out;

    const int n = in_sizes[0] / FEAT;                    // 100000
    const int e = in_sizes[1] / 2;                       // 1600000
    const int nb = (n + BIN_NODES - 1) / BIN_NODES;      // 782
    const int nblk = (e + TILE_EDGES - 1) / TILE_EDGES;  // 196
    const int M = nb * nblk;                             // 153k
    const int nbks = (M + 255) / 256;                    // 599 <= 1024

    // Workspace (256B-aligned). `packed` aliases `acc1` (packed dead after
    // degsort, acc1 first written by pull1).
    char* ws = (char*)d_ws;
    size_t off = 0;
    auto alloc = [&](size_t bytes) { char* p = ws + off; off = (off + bytes + 255) & ~(size_t)255; return p; };
    int*    mat       = (int*)   alloc((size_t)M * 4);
    int*    bsum      = (int*)   alloc((size_t)nbks * 4);
    float*  dis       = (float*) alloc((size_t)n * 4);
    int*    row_start = (int*)   alloc((size_t)(n + 1) * 4);
    int*    recs      = (int*)   alloc((size_t)e * 4);
    __half* h         = (__half*)alloc((size_t)n * FEAT * 2);
    float*  acc1      = (float*) alloc((size_t)n * FEAT * 4);
    int*    packed    = (int*)acc1;   // e*4 = 6.4MB <= 12.8MB

    const size_t ldsA = (size_t)(BWAVES * nb + 1) * 4;   // ~50 KB
    const size_t ldsC = (size_t)(nb + 1) * 4;            // ~3.1 KB
    const int gNode = (n + 7) / 8;

    // CSR build (round-10 proven)
    binA_kernel<<<nblk, 1024, ldsA, stream>>>(eidx_raw, mat, e, nb);
    scan1_kernel<<<nbks, 256, 0, stream>>>(mat, bsum, M, nb, nblk);
    scan2_kernel<<<1, 1024, 0, stream>>>(bsum, nbks);
    binC_kernel<<<nblk, 1024, ldsC, stream>>>(eidx_raw, mat, bsum, packed, e, nb, nblk);
    degsort_kernel<<<nb, 1024, 0, stream>>>(packed, mat, bsum, dis, row_start,
                                            recs, e, n, nb, nblk);

    // Layer 1
    matmul_kernel<<<gNode, 256, 0, stream>>>(x, W1, dis, h, n, 0);
    pull_kernel<<<gNode, 256, 0, stream>>>(recs, row_start, h, dis, b1, acc1, n, 0);

    // Layer 2 (relu on read of acc1; final relu fused in writeout)
    matmul_kernel<<<gNode, 256, 0, stream>>>(acc1, W2, dis, h, n, 1);
    pull_kernel<<<gNode, 256, 0, stream>>>(recs, row_start, h, dis, b2, out, n, 1);
}

// Round 15
// 231.632 us; speedup vs baseline: 1.1021x; 1.0033x over previous
//
#include <hip/hip_runtime.h>
#include <hip/hip_fp16.h>

#define FEAT 32
#define BIN_NODES 128
#define BIN_SHIFT 7
#define TILE_EDGES 4096   // edges per build block (391 blocks -> all 256 CUs covered)
#define BWAVES 16         // waves per build block (1024 threads)
#define SRC_BITS 20
#define SRC_MASK 0xFFFFF

// Block-local int64-vs-int32 detection: odd 32-bit words of an int64 index
// array (values < 2^31) are all zero; for int32 they are random node ids.
__device__ __forceinline__ int block_detect_int64(const int* __restrict__ raw32, int* nz) {
    if (threadIdx.x == 0) *nz = 0;
    __syncthreads();
    if (raw32[2 * threadIdx.x + 1] != 0) *nz = 1;
    __syncthreads();
    return (*nz == 0) ? 1 : 0;
}

__device__ __forceinline__ int load_idx(const void* raw, int f, long long i) {
    return f ? (int)((const long long*)raw)[i] : ((const int*)raw)[i];
}

// Phase A: per-(tile,bin) histogram, 16 wave-private copies (1024 threads).
__global__ __launch_bounds__(1024)
void binA_kernel(const void* __restrict__ raw, int* __restrict__ mat, int e, int nb) {
    extern __shared__ int hist[];  // BWAVES*nb + 1
    int t = threadIdx.x;
    for (int i = t; i < BWAVES * nb; i += 1024) hist[i] = 0;
    int f = block_detect_int64((const int*)raw, &hist[BWAVES * nb]);
    int w = t >> 6, lane = t & 63;
    long long base = (long long)blockIdx.x * TILE_EDGES;
    int cnt = (int)min((long long)TILE_EDGES, (long long)e - base);
    int* hw = hist + w * nb;
    const int seg = TILE_EDGES / BWAVES;  // 256 edges per wave
    int wbeg = w * seg;
    int wend = min(wbeg + seg, cnt);
    for (int i = wbeg + lane; i < wend; i += 64) {
        int d = load_idx(raw, f, (long long)e + base + i);
        atomicAdd(&hw[d >> BIN_SHIFT], 1);
    }
    __syncthreads();
    for (int b = t; b < nb; b += 1024) {
        int s = 0;
#pragma unroll
        for (int w2 = 0; w2 < BWAVES; ++w2) s += hist[w2 * nb + b];
        mat[blockIdx.x * nb + b] = s;
    }
}

// logical L = b*nblk + k (bin-major) <-> physical p = k*nb + b
__device__ __forceinline__ int l2p(int L, int nb, int nblk) {
    int b = L / nblk;
    int k = L - b * nblk;
    return k * nb + b;
}

__global__ void scan1_kernel(int* __restrict__ mat, int* __restrict__ bsum,
                             int M, int nb, int nblk) {
    __shared__ int sd[256];
    int t = threadIdx.x;
    int L = blockIdx.x * 256 + t;
    int p = 0, v = 0;
    if (L < M) { p = l2p(L, nb, nblk); v = mat[p]; }
    sd[t] = v;
    __syncthreads();
    for (int off = 1; off < 256; off <<= 1) {
        int add = (t >= off) ? sd[t - off] : 0;
        __syncthreads();
        sd[t] += add;
        __syncthreads();
    }
    if (L < M) mat[p] = sd[t] - v;   // exclusive within scan-block
    if (t == 255) bsum[blockIdx.x] = sd[t];
}

// Single-block scan, K elements per thread (K<=4 by construction; proven r8).
__global__ void scan2_kernel(int* __restrict__ bsum, int nbks) {
    __shared__ int sd[1024];
    int t = threadIdx.x;
    int K = (nbks + 1023) >> 10;
    if (K > 4) K = 4;
    int base = t * K;
    int loc[4] = {0, 0, 0, 0};
    int s = 0;
    for (int k = 0; k < K; ++k) {
        int v = (base + k < nbks) ? bsum[base + k] : 0;
        loc[k] = s; s += v;
    }
    sd[t] = s;
    __syncthreads();
    for (int off = 1; off < 1024; off <<= 1) {
        int add = (t >= off) ? sd[t - off] : 0;
        __syncthreads();
        sd[t] += add;
        __syncthreads();
    }
    int excl = sd[t] - s;
    for (int k = 0; k < K; ++k) if (base + k < nbks) bsum[base + k] = excl + loc[k];
}

// Phase C: scatter packed records grouped by bin (1024 threads; block-shared
// cursors). rec = src | dst_local<<20.
__global__ __launch_bounds__(1024)
void binC_kernel(const void* __restrict__ raw, const int* __restrict__ mat,
                 const int* __restrict__ bsum, int* __restrict__ packed,
                 int e, int nb, int nblk) {
    extern __shared__ int cur[];  // nb + 1
    int t = threadIdx.x;
    int f = block_detect_int64((const int*)raw, &cur[nb]);
    for (int i = t; i < nb; i += 1024)
        cur[i] = mat[blockIdx.x * nb + i] + bsum[(i * nblk + blockIdx.x) >> 8];
    __syncthreads();
    long long base = (long long)blockIdx.x * TILE_EDGES;
    int cnt = (int)min((long long)TILE_EDGES, (long long)e - base);
    for (int i = t; i < cnt; i += 1024) {
        long long ei = base + i;
        int s = load_idx(raw, f, ei);
        int d = load_idx(raw, f, (long long)e + ei);
        int b = d >> BIN_SHIFT;
        int pos = atomicAdd(&cur[b], 1);
        packed[pos] = s | ((d & (BIN_NODES - 1)) << SRC_BITS);
    }
}

// Per-bin: 16 wave-private LDS histograms -> scan -> dis/row_start + per-wave
// base cursors, then contention-free counting-sort (recs = src, 4B).
__global__ __launch_bounds__(1024)
void degsort_kernel(const int* __restrict__ packed, const int* __restrict__ mat,
                    const int* __restrict__ bsum, float* __restrict__ dis,
                    int* __restrict__ row_start, int* __restrict__ recs,
                    int e, int n, int nb, int nblk) {
    __shared__ int cnt[BWAVES][BIN_NODES];
    __shared__ int wcur[BWAVES][BIN_NODES];
    __shared__ int exc[BIN_NODES];
    int b = blockIdx.x, t = threadIdx.x;
    int w = t >> 6;
    for (int i = t; i < BWAVES * BIN_NODES; i += 1024) ((int*)cnt)[i] = 0;
    __syncthreads();
    int start = mat[b] + bsum[(b * nblk) >> 8];
    int end = (b + 1 < nb) ? (mat[b + 1] + bsum[((b + 1) * nblk) >> 8]) : e;
    for (int i = start + t; i < end; i += 1024)
        atomicAdd(&cnt[w][packed[i] >> SRC_BITS], 1);
    __syncthreads();
    if (t < BIN_NODES) {
        int s = 0;
#pragma unroll
        for (int w2 = 0; w2 < BWAVES; ++w2) s += cnt[w2][t];
        exc[t] = s;
    }
    __syncthreads();
    for (int off = 1; off < BIN_NODES; off <<= 1) {
        int v = 0;
        if (t < BIN_NODES && t >= off) v = exc[t - off];
        __syncthreads();
        if (t < BIN_NODES) exc[t] += v;
        __syncthreads();
    }
    if (t < BIN_NODES) {
        int tot = 0;
#pragma unroll
        for (int w2 = 0; w2 < BWAVES; ++w2) tot += cnt[w2][t];
        int rs = start + exc[t] - tot;   // inclusive -> exclusive
        int run = rs;
#pragma unroll
        for (int w2 = 0; w2 < BWAVES; ++w2) { wcur[w2][t] = run; run += cnt[w2][t]; }
        int node = b * BIN_NODES + t;
        if (node < n) {
            dis[node] = rsqrtf((float)tot + 1.0f);
            row_start[node] = rs;
        }
    }
    if (b == 0 && t == 128) row_start[n] = e;  // sentinel
    __syncthreads();
    for (int i = start + t; i < end; i += 1024) {
        int rec = packed[i];
        int pos = atomicAdd(&wcur[w][rec >> SRC_BITS], 1);
        recs[pos] = rec & SRC_MASK;
    }
}

// h~ = fp16( dis * (act(in) @ W) )   (8 nodes x 32 lanes per block, W in LDS)
__global__ void matmul_kernel(const float* __restrict__ in, const float* __restrict__ W,
                              const float* __restrict__ dis, __half* __restrict__ h,
                              int n, int relu_in) {
    __shared__ float Wl[FEAT * FEAT];
    int tid = threadIdx.x;
    for (int i = tid; i < FEAT * FEAT; i += 256) Wl[i] = W[i];
    __syncthreads();
    int node = blockIdx.x * 8 + (tid >> 5);
    int j = tid & 31;
    if (node >= n) return;
    float xv = in[node * FEAT + j];
    if (relu_in) xv = fmaxf(xv, 0.0f);
    float sum = 0.0f;
#pragma unroll
    for (int k = 0; k < FEAT; ++k) sum = fmaf(__shfl(xv, k, 32), Wl[k * FEAT + j], sum);
    h[node * FEAT + j] = __float2half(dis[node] * sum);
}

// Pull: out[d] = act( dis[d] * (sum_{s in N(d)} h~[s] + h~[d]) + bias ).
// 32 lanes/node = 8 record-slots x 4 feature-lanes (float4 = 8 halves each);
// slots interleave over the window so average-degree rows keep ALL 8 slots
// issuing gathers (max MLP). MSHR/latency-bound: (256,6) measured best.
__global__ __launch_bounds__(256, 6)
void pull_kernel(const int* __restrict__ recs, const int* __restrict__ row_start,
                 const __half* __restrict__ h, const float* __restrict__ dis,
                 const float* __restrict__ bias, float* __restrict__ out,
                 int n, int relu_out) {
    int t = threadIdx.x;
    int node = blockIdx.x * 8 + (t >> 5);
    if (node >= n) return;
    int l32 = t & 31;
    int sub = l32 >> 2;   // record slot 0..7
    int fb = l32 & 3;     // float4 feature block (8 halves)
    int start = row_start[node];
    int deg = row_start[node + 1] - start;
    const float4* h4 = (const float4*)h;  // 8 halves per float4, 4 per row
    float s0 = 0, s1 = 0, s2 = 0, s3 = 0, s4 = 0, s5 = 0, s6 = 0, s7 = 0;
    for (int r0 = 0; r0 < deg; r0 += 64) {
#pragma unroll
        for (int w = 0; w < 8; ++w) {
            int r = r0 + w * 8 + sub;
            if (r < deg) {
                int s = recs[start + r];
                float4 v = h4[(size_t)s * 4 + fb];
                const __half2* hp = (const __half2*)&v;
                float2 a = __half22float2(hp[0]);
                float2 b = __half22float2(hp[1]);
                float2 c = __half22float2(hp[2]);
                float2 d = __half22float2(hp[3]);
                s0 += a.x; s1 += a.y; s2 += b.x; s3 += b.y;
                s4 += c.x; s5 += c.y; s6 += d.x; s7 += d.y;
            }
        }
    }
    // reduce across the 8 record slots (xor 4,8,16 stays within the 32-group)
#pragma unroll
    for (int m = 4; m <= 16; m <<= 1) {
        s0 += __shfl_xor(s0, m, 64); s1 += __shfl_xor(s1, m, 64);
        s2 += __shfl_xor(s2, m, 64); s3 += __shfl_xor(s3, m, 64);
        s4 += __shfl_xor(s4, m, 64); s5 += __shfl_xor(s5, m, 64);
        s6 += __shfl_xor(s6, m, 64); s7 += __shfl_xor(s7, m, 64);
    }
    if (sub == 0) {
        float dn = dis[node];
        float4 hv = h4[(size_t)node * 4 + fb];   // self-loop: + h~[node]
        const __half2* hp = (const __half2*)&hv;
        float2 a = __half22float2(hp[0]);
        float2 b = __half22float2(hp[1]);
        float2 c = __half22float2(hp[2]);
        float2 d = __half22float2(hp[3]);
        const float4* bv4 = (const float4*)bias;
        float4 b0 = bv4[fb * 2], b1 = bv4[fb * 2 + 1];
        float4 o0, o1;
        o0.x = fmaf(dn, s0 + a.x, b0.x);
        o0.y = fmaf(dn, s1 + a.y, b0.y);
        o0.z = fmaf(dn, s2 + b.x, b0.z);
        o0.w = fmaf(dn, s3 + b.y, b0.w);
        o1.x = fmaf(dn, s4 + c.x, b1.x);
        o1.y = fmaf(dn, s5 + c.y, b1.y);
        o1.z = fmaf(dn, s6 + d.x, b1.z);
        o1.w = fmaf(dn, s7 + d.y, b1.w);
        if (relu_out) {
            o0.x = fmaxf(o0.x, 0.0f); o0.y = fmaxf(o0.y, 0.0f);
            o0.z = fmaxf(o0.z, 0.0f); o0.w = fmaxf(o0.w, 0.0f);
            o1.x = fmaxf(o1.x, 0.0f); o1.y = fmaxf(o1.y, 0.0f);
            o1.z = fmaxf(o1.z, 0.0f); o1.w = fmaxf(o1.w, 0.0f);
        }
        ((float4*)out)[(size_t)node * 8 + fb * 2] = o0;
        ((float4*)out)[(size_t)node * 8 + fb * 2 + 1] = o1;
    }
}

extern "C" void kernel_launch(void* const* d_in, const int* in_sizes, int n_in,
                              void* d_out, int out_size, void* d_ws, size_t ws_size,
                              hipStream_t stream) {
    const float* x = (const float*)d_in[0];
    const void* eidx_raw = d_in[1];
    const float* W1 = (const float*)d_in[2];
    const float* b1 = (const float*)d_in[3];
    const float* W2 = (const float*)d_in[4];
    const float* b2 = (const float*)d_in[5];
    float* out = (float*)d_out;

    const int n = in_sizes[0] / FEAT;                    // 100000
    const int e = in_sizes[1] / 2;                       // 1600000
    const int nb = (n + BIN_NODES - 1) / BIN_NODES;      // 782
    const int nblk = (e + TILE_EDGES - 1) / TILE_EDGES;  // 391
    const int M = nb * nblk;                             // ~306k
    const int nbks = (M + 255) / 256;                    // 1195 (scan2 K=2)

    // Workspace (256B-aligned). `packed` aliases `acc1` (packed dead after
    // degsort, acc1 first written by pull1).
    char* ws = (char*)d_ws;
    size_t off = 0;
    auto alloc = [&](size_t bytes) { char* p = ws + off; off = (off + bytes + 255) & ~(size_t)255; return p; };
    int*    mat       = (int*)   alloc((size_t)M * 4);
    int*    bsum      = (int*)   alloc((size_t)nbks * 4);
    float*  dis       = (float*) alloc((size_t)n * 4);
    int*    row_start = (int*)   alloc((size_t)(n + 1) * 4);
    int*    recs      = (int*)   alloc((size_t)e * 4);
    __half* h         = (__half*)alloc((size_t)n * FEAT * 2);
    float*  acc1      = (float*) alloc((size_t)n * FEAT * 4);
    int*    packed    = (int*)acc1;   // e*4 = 6.4MB <= 12.8MB

    const size_t ldsA = (size_t)(BWAVES * nb + 1) * 4;   // ~50 KB
    const size_t ldsC = (size_t)(nb + 1) * 4;            // ~3.1 KB
    const int gNode = (n + 7) / 8;

    // CSR build
    binA_kernel<<<nblk, 1024, ldsA, stream>>>(eidx_raw, mat, e, nb);
    scan1_kernel<<<nbks, 256, 0, stream>>>(mat, bsum, M, nb, nblk);
    scan2_kernel<<<1, 1024, 0, stream>>>(bsum, nbks);
    binC_kernel<<<nblk, 1024, ldsC, stream>>>(eidx_raw, mat, bsum, packed, e, nb, nblk);
    degsort_kernel<<<nb, 1024, 0, stream>>>(packed, mat, bsum, dis, row_start,
                                            recs, e, n, nb, nblk);

    // Layer 1
    matmul_kernel<<<gNode, 256, 0, stream>>>(x, W1, dis, h, n, 0);
    pull_kernel<<<gNode, 256, 0, stream>>>(recs, row_start, h, dis, b1, acc1, n, 0);

    // Layer 2 (relu on read of acc1; final relu fused in writeout)
    matmul_kernel<<<gNode, 256, 0, stream>>>(acc1, W2, dis, h, n, 1);
    pull_kernel<<<gNode, 256, 0, stream>>>(recs, row_start, h, dis, b2, out, n, 1);
}

// Round 16
// 228.293 us; speedup vs baseline: 1.1182x; 1.0146x over previous
//
#include <hip/hip_runtime.h>
#include <hip/hip_fp16.h>

#define FEAT 32
#define BIN_NODES 128
#define BIN_SHIFT 7
#define TILE_EDGES 8192   // edges per build block
#define BWAVES 16         // waves per build block (1024 threads)
#define SRC_BITS 20
#define SRC_MASK 0xFFFFF

// Block-local int64-vs-int32 detection: odd 32-bit words of an int64 index
// array (values < 2^31) are all zero; for int32 they are random node ids.
__device__ __forceinline__ int block_detect_int64(const int* __restrict__ raw32, int* nz) {
    if (threadIdx.x == 0) *nz = 0;
    __syncthreads();
    if (raw32[2 * threadIdx.x + 1] != 0) *nz = 1;
    __syncthreads();
    return (*nz == 0) ? 1 : 0;
}

__device__ __forceinline__ int load_idx(const void* raw, int f, long long i) {
    return f ? (int)((const long long*)raw)[i] : ((const int*)raw)[i];
}

// Phase A: per-(tile,bin) histogram, 16 wave-private copies (1024 threads).
__global__ __launch_bounds__(1024)
void binA_kernel(const void* __restrict__ raw, int* __restrict__ mat, int e, int nb) {
    extern __shared__ int hist[];  // BWAVES*nb + 1
    int t = threadIdx.x;
    for (int i = t; i < BWAVES * nb; i += 1024) hist[i] = 0;
    int f = block_detect_int64((const int*)raw, &hist[BWAVES * nb]);
    int w = t >> 6, lane = t & 63;
    long long base = (long long)blockIdx.x * TILE_EDGES;
    int cnt = (int)min((long long)TILE_EDGES, (long long)e - base);
    int* hw = hist + w * nb;
    const int seg = TILE_EDGES / BWAVES;  // 512 edges per wave
    int wbeg = w * seg;
    int wend = min(wbeg + seg, cnt);
    for (int i = wbeg + lane; i < wend; i += 64) {
        int d = load_idx(raw, f, (long long)e + base + i);
        atomicAdd(&hw[d >> BIN_SHIFT], 1);
    }
    __syncthreads();
    for (int b = t; b < nb; b += 1024) {
        int s = 0;
#pragma unroll
        for (int w2 = 0; w2 < BWAVES; ++w2) s += hist[w2 * nb + b];
        mat[blockIdx.x * nb + b] = s;
    }
}

// logical L = b*nblk + k (bin-major) <-> physical p = k*nb + b
__device__ __forceinline__ int l2p(int L, int nb, int nblk) {
    int b = L / nblk;
    int k = L - b * nblk;
    return k * nb + b;
}

__global__ void scan1_kernel(int* __restrict__ mat, int* __restrict__ bsum,
                             int M, int nb, int nblk) {
    __shared__ int sd[256];
    int t = threadIdx.x;
    int L = blockIdx.x * 256 + t;
    int p = 0, v = 0;
    if (L < M) { p = l2p(L, nb, nblk); v = mat[p]; }
    sd[t] = v;
    __syncthreads();
    for (int off = 1; off < 256; off <<= 1) {
        int add = (t >= off) ? sd[t - off] : 0;
        __syncthreads();
        sd[t] += add;
        __syncthreads();
    }
    if (L < M) mat[p] = sd[t] - v;   // exclusive within scan-block
    if (t == 255) bsum[blockIdx.x] = sd[t];
}

__global__ void scan2_kernel(int* __restrict__ bsum, int nbks) {
    __shared__ int sd[1024];
    int t = threadIdx.x;
    int v = (t < nbks) ? bsum[t] : 0;
    sd[t] = v;
    __syncthreads();
    for (int off = 1; off < 1024; off <<= 1) {
        int add = (t >= off) ? sd[t - off] : 0;
        __syncthreads();
        sd[t] += add;
        __syncthreads();
    }
    if (t < nbks) bsum[t] = sd[t] - v;
}

// Phase C: scatter packed records grouped by bin (1024 threads; block-shared
// cursors). rec = src | dst_local<<20.
__global__ __launch_bounds__(1024)
void binC_kernel(const void* __restrict__ raw, const int* __restrict__ mat,
                 const int* __restrict__ bsum, int* __restrict__ packed,
                 int e, int nb, int nblk) {
    extern __shared__ int cur[];  // nb + 1
    int t = threadIdx.x;
    int f = block_detect_int64((const int*)raw, &cur[nb]);
    for (int i = t; i < nb; i += 1024)
        cur[i] = mat[blockIdx.x * nb + i] + bsum[(i * nblk + blockIdx.x) >> 8];
    __syncthreads();
    long long base = (long long)blockIdx.x * TILE_EDGES;
    int cnt = (int)min((long long)TILE_EDGES, (long long)e - base);
    for (int i = t; i < cnt; i += 1024) {
        long long ei = base + i;
        int s = load_idx(raw, f, ei);
        int d = load_idx(raw, f, (long long)e + ei);
        int b = d >> BIN_SHIFT;
        int pos = atomicAdd(&cur[b], 1);
        packed[pos] = s | ((d & (BIN_NODES - 1)) << SRC_BITS);
    }
}

// Per-bin: 16 wave-private LDS histograms -> scan -> dis/row_start + per-wave
// base cursors, then contention-free counting-sort (recs = src, 4B).
__global__ __launch_bounds__(1024)
void degsort_kernel(const int* __restrict__ packed, const int* __restrict__ mat,
                    const int* __restrict__ bsum, float* __restrict__ dis,
                    int* __restrict__ row_start, int* __restrict__ recs,
                    int e, int n, int nb, int nblk) {
    __shared__ int cnt[BWAVES][BIN_NODES];
    __shared__ int wcur[BWAVES][BIN_NODES];
    __shared__ int exc[BIN_NODES];
    int b = blockIdx.x, t = threadIdx.x;
    int w = t >> 6;
    for (int i = t; i < BWAVES * BIN_NODES; i += 1024) ((int*)cnt)[i] = 0;
    __syncthreads();
    int start = mat[b] + bsum[(b * nblk) >> 8];
    int end = (b + 1 < nb) ? (mat[b + 1] + bsum[((b + 1) * nblk) >> 8]) : e;
    for (int i = start + t; i < end; i += 1024)
        atomicAdd(&cnt[w][packed[i] >> SRC_BITS], 1);
    __syncthreads();
    if (t < BIN_NODES) {
        int s = 0;
#pragma unroll
        for (int w2 = 0; w2 < BWAVES; ++w2) s += cnt[w2][t];
        exc[t] = s;
    }
    __syncthreads();
    for (int off = 1; off < BIN_NODES; off <<= 1) {
        int v = 0;
        if (t < BIN_NODES && t >= off) v = exc[t - off];
        __syncthreads();
        if (t < BIN_NODES) exc[t] += v;
        __syncthreads();
    }
    if (t < BIN_NODES) {
        int tot = 0;
#pragma unroll
        for (int w2 = 0; w2 < BWAVES; ++w2) tot += cnt[w2][t];
        int rs = start + exc[t] - tot;   // inclusive -> exclusive
        int run = rs;
#pragma unroll
        for (int w2 = 0; w2 < BWAVES; ++w2) { wcur[w2][t] = run; run += cnt[w2][t]; }
        int node = b * BIN_NODES + t;
        if (node < n) {
            dis[node] = rsqrtf((float)tot + 1.0f);
            row_start[node] = rs;
        }
    }
    if (b == 0 && t == 128) row_start[n] = e;  // sentinel
    __syncthreads();
    for (int i = start + t; i < end; i += 1024) {
        int rec = packed[i];
        int pos = atomicAdd(&wcur[w][rec >> SRC_BITS], 1);
        recs[pos] = rec & SRC_MASK;
    }
}

// h~ = fp16( dis * (act(in) @ W) )   (8 nodes x 32 lanes per block, W in LDS)
__global__ void matmul_kernel(const float* __restrict__ in, const float* __restrict__ W,
                              const float* __restrict__ dis, __half* __restrict__ h,
                              int n, int relu_in) {
    __shared__ float Wl[FEAT * FEAT];
    int tid = threadIdx.x;
    for (int i = tid; i < FEAT * FEAT; i += 256) Wl[i] = W[i];
    __syncthreads();
    int node = blockIdx.x * 8 + (tid >> 5);
    int j = tid & 31;
    if (node >= n) return;
    float xv = in[node * FEAT + j];
    if (relu_in) xv = fmaxf(xv, 0.0f);
    float sum = 0.0f;
#pragma unroll
    for (int k = 0; k < FEAT; ++k) sum = fmaf(__shfl(xv, k, 32), Wl[k * FEAT + j], sum);
    h[node * FEAT + j] = __float2half(dis[node] * sum);
}

// Pull: out[d] = act( dis[d] * (sum_{s in N(d)} h~[s] + h~[d]) + bias ).
// 32 lanes/node = 8 record-slots x 4 feature-lanes (float4 = 8 halves each);
// slots interleave over the window so average-degree rows keep ALL 8 slots
// issuing gathers (max MLP). MSHR/latency-bound: (256,6) measured best.
__global__ __launch_bounds__(256, 6)
void pull_kernel(const int* __restrict__ recs, const int* __restrict__ row_start,
                 const __half* __restrict__ h, const float* __restrict__ dis,
                 const float* __restrict__ bias, float* __restrict__ out,
                 int n, int relu_out) {
    int t = threadIdx.x;
    int node = blockIdx.x * 8 + (t >> 5);
    if (node >= n) return;
    int l32 = t & 31;
    int sub = l32 >> 2;   // record slot 0..7
    int fb = l32 & 3;     // float4 feature block (8 halves)
    int start = row_start[node];
    int deg = row_start[node + 1] - start;
    const float4* h4 = (const float4*)h;  // 8 halves per float4, 4 per row
    float s0 = 0, s1 = 0, s2 = 0, s3 = 0, s4 = 0, s5 = 0, s6 = 0, s7 = 0;
    for (int r0 = 0; r0 < deg; r0 += 64) {
#pragma unroll
        for (int w = 0; w < 8; ++w) {
            int r = r0 + w * 8 + sub;
            if (r < deg) {
                int s = recs[start + r];
                float4 v = h4[(size_t)s * 4 + fb];
                const __half2* hp = (const __half2*)&v;
                float2 a = __half22float2(hp[0]);
                float2 b = __half22float2(hp[1]);
                float2 c = __half22float2(hp[2]);
                float2 d = __half22float2(hp[3]);
                s0 += a.x; s1 += a.y; s2 += b.x; s3 += b.y;
                s4 += c.x; s5 += c.y; s6 += d.x; s7 += d.y;
            }
        }
    }
    // reduce across the 8 record slots (xor 4,8,16 stays within the 32-group)
#pragma unroll
    for (int m = 4; m <= 16; m <<= 1) {
        s0 += __shfl_xor(s0, m, 64); s1 += __shfl_xor(s1, m, 64);
        s2 += __shfl_xor(s2, m, 64); s3 += __shfl_xor(s3, m, 64);
        s4 += __shfl_xor(s4, m, 64); s5 += __shfl_xor(s5, m, 64);
        s6 += __shfl_xor(s6, m, 64); s7 += __shfl_xor(s7, m, 64);
    }
    if (sub == 0) {
        float dn = dis[node];
        float4 hv = h4[(size_t)node * 4 + fb];   // self-loop: + h~[node]
        const __half2* hp = (const __half2*)&hv;
        float2 a = __half22float2(hp[0]);
        float2 b = __half22float2(hp[1]);
        float2 c = __half22float2(hp[2]);
        float2 d = __half22float2(hp[3]);
        const float4* bv4 = (const float4*)bias;
        float4 b0 = bv4[fb * 2], b1 = bv4[fb * 2 + 1];
        float4 o0, o1;
        o0.x = fmaf(dn, s0 + a.x, b0.x);
        o0.y = fmaf(dn, s1 + a.y, b0.y);
        o0.z = fmaf(dn, s2 + b.x, b0.z);
        o0.w = fmaf(dn, s3 + b.y, b0.w);
        o1.x = fmaf(dn, s4 + c.x, b1.x);
        o1.y = fmaf(dn, s5 + c.y, b1.y);
        o1.z = fmaf(dn, s6 + d.x, b1.z);
        o1.w = fmaf(dn, s7 + d.y, b1.w);
        if (relu_out) {
            o0.x = fmaxf(o0.x, 0.0f); o0.y = fmaxf(o0.y, 0.0f);
            o0.z = fmaxf(o0.z, 0.0f); o0.w = fmaxf(o0.w, 0.0f);
            o1.x = fmaxf(o1.x, 0.0f); o1.y = fmaxf(o1.y, 0.0f);
            o1.z = fmaxf(o1.z, 0.0f); o1.w = fmaxf(o1.w, 0.0f);
        }
        ((float4*)out)[(size_t)node * 8 + fb * 2] = o0;
        ((float4*)out)[(size_t)node * 8 + fb * 2 + 1] = o1;
    }
}

extern "C" void kernel_launch(void* const* d_in, const int* in_sizes, int n_in,
                              void* d_out, int out_size, void* d_ws, size_t ws_size,
                              hipStream_t stream) {
    const float* x = (const float*)d_in[0];
    const void* eidx_raw = d_in[1];
    const float* W1 = (const float*)d_in[2];
    const float* b1 = (const float*)d_in[3];
    const float* W2 = (const float*)d_in[4];
    const float* b2 = (const float*)d_in[5];
    float* out = (float*)d_out;

    const int n = in_sizes[0] / FEAT;                    // 100000
    const int e = in_sizes[1] / 2;                       // 1600000
    const int nb = (n + BIN_NODES - 1) / BIN_NODES;      // 782
    const int nblk = (e + TILE_EDGES - 1) / TILE_EDGES;  // 196
    const int M = nb * nblk;                             // 153k
    const int nbks = (M + 255) / 256;                    // 599 <= 1024

    // Workspace (256B-aligned). `packed` aliases `acc1` (packed dead after
    // degsort, acc1 first written by pull1).
    char* ws = (char*)d_ws;
    size_t off = 0;
    auto alloc = [&](size_t bytes) { char* p = ws + off; off = (off + bytes + 255) & ~(size_t)255; return p; };
    int*    mat       = (int*)   alloc((size_t)M * 4);
    int*    bsum      = (int*)   alloc((size_t)nbks * 4);
    float*  dis       = (float*) alloc((size_t)n * 4);
    int*    row_start = (int*)   alloc((size_t)(n + 1) * 4);
    int*    recs      = (int*)   alloc((size_t)e * 4);
    __half* h         = (__half*)alloc((size_t)n * FEAT * 2);
    float*  acc1      = (float*) alloc((size_t)n * FEAT * 4);
    int*    packed    = (int*)acc1;   // e*4 = 6.4MB <= 12.8MB

    const size_t ldsA = (size_t)(BWAVES * nb + 1) * 4;   // ~50 KB
    const size_t ldsC = (size_t)(nb + 1) * 4;            // ~3.1 KB
    const int gNode = (n + 7) / 8;

    // CSR build (round-10 proven)
    binA_kernel<<<nblk, 1024, ldsA, stream>>>(eidx_raw, mat, e, nb);
    scan1_kernel<<<nbks, 256, 0, stream>>>(mat, bsum, M, nb, nblk);
    scan2_kernel<<<1, 1024, 0, stream>>>(bsum, nbks);
    binC_kernel<<<nblk, 1024, ldsC, stream>>>(eidx_raw, mat, bsum, packed, e, nb, nblk);
    degsort_kernel<<<nb, 1024, 0, stream>>>(packed, mat, bsum, dis, row_start,
                                            recs, e, n, nb, nblk);

    // Layer 1
    matmul_kernel<<<gNode, 256, 0, stream>>>(x, W1, dis, h, n, 0);
    pull_kernel<<<gNode, 256, 0, stream>>>(recs, row_start, h, dis, b1, acc1, n, 0);

    // Layer 2 (relu on read of acc1; final relu fused in writeout)
    matmul_kernel<<<gNode, 256, 0, stream>>>(acc1, W2, dis, h, n, 1);
    pull_kernel<<<gNode, 256, 0, stream>>>(recs, row_start, h, dis, b2, out, n, 1);
}